// Round 3
// baseline (3263.751 us; speedup 1.0000x reference)
//
#include <hip/hip_runtime.h>
#include <math.h>

// Problem constants
#define NN 400
#define TPB 512          // 8 waves, 2 waves/SIMD; each wave holds 3-4 register-resident A-tiles
#define KP 424           // padded K stride in fp16 elems

// workspace layout (32-bit indices)
#define XRAW_OFF 1024    // 3200 floats
#define HINP_OFF 4224    // 400 floats
#define CL_OFF   4624    // 2400 floats (projected readout c from k_pre2)

#define TAU_X 0.05f
#define TAU_M 0.2f
#define A1C 0.16f
#define A2C 0.048f
#define A3C 0.045f
#define DHC 0.001f
#define L1C 0.3f
#define L2C 0.33f

typedef unsigned long long ull;
typedef _Float16 f16;
typedef _Float16 __attribute__((ext_vector_type(8))) half8;
typedef float __attribute__((ext_vector_type(4))) f32x4;

// K1: xraw[n][b] = (top_obs @ xstars_prms)[n,b] + xstars_tar[b][n]; hinp[n] = spont[n]-(W@spont)[n]
__global__ __launch_bounds__(64) void k_pre1(const float* __restrict__ topo,
        const float* __restrict__ xp, const float* __restrict__ W,
        const float* __restrict__ sp, const float* __restrict__ iw,
        const float* __restrict__ des, float* __restrict__ ws)
{
    const int n = blockIdx.x, lane = threadIdx.x;
    float a0=0,a1=0,a2=0,a3=0,a4=0,a5=0,a6=0,a7=0, ah=0;
    for (int k = lane; k < NN; k += 64) {
        float to = topo[n*NN + k];
        float wv = W[n*NN + k];
        float s  = sp[k];
        const float* xr = xp + k*8;
        a0 = fmaf(to, xr[0], a0); a1 = fmaf(to, xr[1], a1);
        a2 = fmaf(to, xr[2], a2); a3 = fmaf(to, xr[3], a3);
        a4 = fmaf(to, xr[4], a4); a5 = fmaf(to, xr[5], a5);
        a6 = fmaf(to, xr[6], a6); a7 = fmaf(to, xr[7], a7);
        ah = fmaf(wv, s, ah);
    }
    #pragma unroll
    for (int m = 1; m < 64; m <<= 1) {
        a0 += __shfl_xor(a0, m, 64); a1 += __shfl_xor(a1, m, 64);
        a2 += __shfl_xor(a2, m, 64); a3 += __shfl_xor(a3, m, 64);
        a4 += __shfl_xor(a4, m, 64); a5 += __shfl_xor(a5, m, 64);
        a6 += __shfl_xor(a6, m, 64); a7 += __shfl_xor(a7, m, 64);
        ah += __shfl_xor(ah, m, 64);
    }
    if (lane == 0) {
        float av[8] = {a0,a1,a2,a3,a4,a5,a6,a7};
        float w0 = iw[n*10 + 0], w1 = iw[n*10 + 1];
        #pragma unroll
        for (int b = 0; b < 8; ++b) {
            float j0 = des[2*b]   - 0.25f;
            float j1 = des[2*b+1] - 0.25f;
            ws[XRAW_OFF + n*8 + b] = av[b] + j0*w0 + j1*w1;
        }
        ws[HINP_OFF + n] = sp[n] - ah;
    }
}

// K2: scale s, Gram solve (fp64), Q, Cl precompute
__global__ __launch_bounds__(64) void k_pre2(const float* __restrict__ cp,
        const float* __restrict__ sp, float* __restrict__ ws)
{
    __shared__ float part[99][65];
    __shared__ float red[99];
    const int lane = threadIdx.x;
    float Sxx[36], Sxs[8], Praw[48], Ps[6];
    float Sss = 0.f;
    #pragma unroll
    for (int q = 0; q < 36; ++q) Sxx[q] = 0.f;
    #pragma unroll
    for (int q = 0; q < 8; ++q) Sxs[q] = 0.f;
    #pragma unroll
    for (int q = 0; q < 48; ++q) Praw[q] = 0.f;
    #pragma unroll
    for (int q = 0; q < 6; ++q) Ps[q] = 0.f;

    for (int n = lane; n < NN; n += 64) {
        float xr[8];
        #pragma unroll
        for (int j = 0; j < 8; ++j) xr[j] = ws[XRAW_OFF + n*8 + j];
        float s = sp[n];
        int q = 0;
        #pragma unroll
        for (int i = 0; i < 8; ++i) {
            Sxs[i] = fmaf(xr[i], s, Sxs[i]);
            #pragma unroll
            for (int j = i; j < 8; ++j) { Sxx[q] = fmaf(xr[i], xr[j], Sxx[q]); ++q; }
        }
        Sss = fmaf(s, s, Sss);
        #pragma unroll
        for (int m = 0; m < 6; ++m) {
            float cv = cp[m*NN + n];
            #pragma unroll
            for (int j = 0; j < 8; ++j) Praw[m*8+j] = fmaf(cv, xr[j], Praw[m*8+j]);
            Ps[m] = fmaf(cv, s, Ps[m]);
        }
    }
    #pragma unroll
    for (int q = 0; q < 36; ++q) part[q][lane] = Sxx[q];
    #pragma unroll
    for (int j = 0; j < 8; ++j) part[36+j][lane] = Sxs[j];
    part[44][lane] = Sss;
    #pragma unroll
    for (int q = 0; q < 48; ++q) part[45+q][lane] = Praw[q];
    #pragma unroll
    for (int m = 0; m < 6; ++m) part[93+m][lane] = Ps[m];
    __syncthreads();
    for (int q = lane; q < 99; q += 64) {
        float acc = 0.f;
        for (int l = 0; l < 64; ++l) acc += part[q][l];
        red[q] = acc;
    }
    __syncthreads();
    if (lane == 0) {
        int IDX[8][8];
        { int q = 0; for (int i = 0; i < 8; ++i) for (int j = i; j < 8; ++j) { IDX[i][j]=q; IDX[j][i]=q; ++q; } }
        float sumsq = 0.f;
        for (int i = 0; i < 8; ++i) sumsq += red[IDX[i][i]];
        double s = sqrt(128.0 / (double)sumsq);   // z = N*B*0.2^2
        double Sssd = (double)red[44];
        double G[9][9];
        for (int i = 0; i < 8; ++i)
            for (int j = 0; j < 8; ++j)
                G[i][j] = s*s*(double)red[IDX[i][j]] + s*((double)red[36+i] + (double)red[36+j]) + Sssd;
        for (int i = 0; i < 8; ++i) { G[i][8] = G[8][i] = s*(double)red[36+i] + Sssd; }
        G[8][8] = Sssd;
        double A[9][18];
        for (int i = 0; i < 9; ++i)
            for (int j = 0; j < 9; ++j) { A[i][j] = G[i][j]; A[i][9+j] = (i==j) ? 1.0 : 0.0; }
        for (int col = 0; col < 9; ++col) {
            int piv = col; double mx = fabs(A[col][col]);
            for (int r = col+1; r < 9; ++r) { double v = fabs(A[r][col]); if (v > mx) { mx = v; piv = r; } }
            if (piv != col) for (int j = 0; j < 18; ++j) { double tt = A[col][j]; A[col][j] = A[piv][j]; A[piv][j] = tt; }
            double pv = A[col][col];
            for (int j = 0; j < 18; ++j) A[col][j] /= pv;
            for (int r = 0; r < 9; ++r) if (r != col) {
                double f = A[r][col];
                for (int j = 0; j < 18; ++j) A[r][j] -= f*A[col][j];
            }
        }
        for (int m = 0; m < 6; ++m) {
            double P[9];
            for (int j = 0; j < 8; ++j) P[j] = s*(double)red[45 + m*8 + j] + (double)red[93+m];
            P[8] = (double)red[93+m];
            for (int j = 0; j < 9; ++j) {
                double qv = 0;
                for (int l = 0; l < 9; ++l) qv += P[l]*A[l][9+j];
                ws[2 + m*9 + j] = (float)qv;
            }
        }
        ws[1] = (float)s;
    }
    __syncthreads();
    // Cl[m][n] = cp[m][n] - s*(Q[m,:8].xraw[n,:]) - sp[n]*sum(Q[m,:])
    {
        float s = ws[1];
        for (int idx = lane; idx < 6*NN; idx += 64) {
            int m = idx / NN, n = idx - m*NN;
            float acc = 0.f, sq = 0.f;
            #pragma unroll
            for (int j = 0; j < 8; ++j) {
                float q = ws[2 + m*9 + j];
                acc = fmaf(q, ws[XRAW_OFF + n*8 + j], acc);
                sq += q;
            }
            sq += ws[2 + m*9 + 8];
            ws[CL_OFF + idx] = cp[idx] - s*acc - sp[n]*sq;
        }
    }
}

// A-fragment loader: W[m][k0..k0+7] fp32 -> fp16; k=400 carries h_inp (r row 400 == 1)
__device__ __forceinline__ half8 load_wfrag(const float* __restrict__ Wg,
        const float* __restrict__ ws, int m, int k0)
{
    half8 a;
    if (k0 + 8 <= 400) {
        float4 x0 = *(const float4*)(Wg + m*400 + k0);
        float4 x1 = *(const float4*)(Wg + m*400 + k0 + 4);
        a[0]=(f16)x0.x; a[1]=(f16)x0.y; a[2]=(f16)x0.z; a[3]=(f16)x0.w;
        a[4]=(f16)x1.x; a[5]=(f16)x1.y; a[6]=(f16)x1.z; a[7]=(f16)x1.w;
    } else {
        #pragma unroll
        for (int j = 0; j < 8; ++j) {
            int k = k0 + j;
            float v = 0.f;
            if (k < 400) v = Wg[m*400 + k];
            else if (k == 400) v = ws[HINP_OFF + m];
            a[j] = (f16)v;
        }
    }
    return a;
}

// Muscle-Cl fragment: rows = muscle index (only 0..5 real), no bias at k=400
__device__ __forceinline__ half8 load_clfrag(const float* __restrict__ cl, int m, int k0)
{
    half8 a;
    #pragma unroll
    for (int j = 0; j < 8; ++j) {
        int k = k0 + j;
        float v = (m < 6 && k < 400) ? cl[m*400 + k] : 0.f;
        a[j] = (f16)v;
    }
    return a;
}

__device__ __forceinline__ void store_r4(f16* dst, float r0, float r1, float r2, float r3) {
    union { f16 h[4]; ull u; } pk;
    pk.h[0] = (f16)r0; pk.h[1] = (f16)r1; pk.h[2] = (f16)r2; pk.h[3] = (f16)r3;
    *(ull*)dst = pk.u;
}

// one Euler step of the 2-link arm + kinematics; lanes 0..7 (one per batch)
__device__ __forceinline__ void arm_step_ode(const float* __restrict__ fr, int lane,
        float& t1, float& t2, float& d1, float& d2, float4& o4)
{
    const float MX[6] = {0.04f,-0.04f,0.f,0.f,0.028f,-0.035f};
    const float MY[6] = {0.f,0.f,0.025f,-0.025f,0.035f,-0.028f};
    float tq0 = 0.f, tq1 = 0.f;
    #pragma unroll
    for (int mm = 0; mm < 6; ++mm) {
        float f = fr[mm*8 + lane];
        tq0 = fmaf(f, MX[mm], tq0);
        tq1 = fmaf(f, MY[mm], tq1);
    }
    float cc2 = cosf(t2), ss2 = sinf(t2);
    float M11 = A1C + 2.f*A2C*cc2;
    float M12 = A3C + A2C*cc2;
    float h = A2C * ss2;
    float C1v = -h * d2 * (2.f*d1 + d2);
    float C2v = h * d1 * d1;
    float rr1 = tq0 - C1v - (0.05f*d1 + 0.025f*d2);
    float rr2 = tq1 - C2v - (0.025f*d1 + 0.05f*d2);
    float det = M11*A3C - M12*M12;
    float dd1 = (A3C*rr1 - M12*rr2) / det;
    float dd2 = (M11*rr2 - M12*rr1) / det;
    t1 += DHC * d1; t2 += DHC * d2;
    d1 += DHC * dd1; d2 += DHC * dd2;
    float t12 = t1 + t2, d12 = d1 + d2;
    float c1v = cosf(t1), s1v = sinf(t1);
    float c12 = cosf(t12), s12 = sinf(t12);
    o4.x = L1C*c1v + L2C*c12;
    o4.y = L1C*s1v + L2C*s12;
    o4.z = -L1C*s1v*d1 - L2C*s12*d12;
    o4.w = L1C*c1v*d1 + L2C*c12*d12;
}

// K3: whole recurrence on ONE CU via MFMA; 8 waves (2 per SIMD) so LDS/VALU/barrier
// stalls of one wave overlap with the partner wave's MFMA issue.
// Tile map (16-row M-tiles, K=424 incl. bias row 400 = h_inp); 26 tiles total:
//   wave0: W 0-3 (4)   wave1: W 4-6    wave2: W 7-9  + arm ODE + out flush
//   wave3: W 10-12     wave4: W 13-15  wave5: W 16-19 (4)
//   wave6: W 20-22     wave7: W 23-24 + muscle-Cl (slot 2) + muscle state
// af[4][13] = 208 VGPR -> fits the 256-reg/wave budget at 2 waves/EU (no spill).
__global__ __launch_bounds__(TPB, 2) void k_run(const int* __restrict__ Tp,
        const float* __restrict__ Wg, const float* __restrict__ sp,
        const float* __restrict__ gg, float* __restrict__ ws,
        float* __restrict__ out)
{
    __shared__ __align__(16) f16 rpl[2][8][KP];     // r planes [batch(8)][neuron k(424)]
    __shared__ float dbuf[10][48];                  // muscle delay ring (wave7)
    __shared__ float frc[2][48];                    // double-buffered: w7 writes, w2 reads
    __shared__ float4 obuf[32][8];                  // 32-step cart out-ring (wave2)

    const int tid = threadIdx.x;
    const int T = *Tp;
    const int wave = tid >> 6, lane = tid & 63;
    const int quad = lane >> 4, col = lane & 15;
    const int bcol = col & 7;
    const float s = ws[1];

    // ---- LDS init ----
    for (int idx = tid; idx < 2*8*KP; idx += TPB) ((f16*)rpl)[idx] = (f16)0.f;
    for (int idx = tid; idx < 480; idx += TPB) ((float*)dbuf)[idx] = 0.f;
    for (int idx = tid; idx < 96; idx += TPB) ((float*)frc)[idx] = 0.f;
    __syncthreads();
    if (tid < 8) { rpl[0][tid][400] = (f16)1.f; rpl[1][tid][400] = (f16)1.f; }

    // ---- tile assignment ----
    const int TBASE = (wave==0)?0 : (wave==1)?4 : (wave==2)?7 : (wave==3)?10 :
                      (wave==4)?13 : (wave==5)?16 : (wave==6)?20 : 23;
    const bool four = (wave == 0) || (wave == 5);
    const int nW = four ? 4 : ((wave == 7) ? 2 : 3);   // W tiles feeding rpl epilogue

    // ---- A-fragments in registers: af[t][kt] ----
    half8 af[4][13];
    #pragma unroll
    for (int t = 0; t < 4; ++t) {
        #pragma unroll
        for (int kt = 0; kt < 13; ++kt) {
            int k0 = kt*32 + quad*8;
            half8 v;
            if (t < nW) {
                v = load_wfrag(Wg, ws, (TBASE + t)*16 + col, k0);
            } else if (wave == 7 && t == 2) {
                v = load_clfrag(ws + CL_OFF, col, k0);
            } else {
                #pragma unroll
                for (int j = 0; j < 8; ++j) v[j] = (f16)0.f;
            }
            af[t][kt] = v;
        }
    }

    // ---- state init: acc = 19*x0 (x lives in accumulator scaled by (1-tau)/tau) ----
    f32x4 acc[4];
    float ca[4][4];
    float msc[4] = {0.f, 0.f, 0.f, 0.f};
    float t1 = 1.f, t2 = 1.f, d1 = 0.f, d2 = 0.f;   // wave2 lanes 0..7
    #pragma unroll
    for (int t = 0; t < 4; ++t)
        #pragma unroll
        for (int r = 0; r < 4; ++r) { acc[t][r] = 0.f; ca[t][r] = 0.f; }
    #pragma unroll
    for (int t = 0; t < 4; ++t) {
        if (t < nW) {
            int n0 = (TBASE + t)*16 + quad*4;
            float rr[4];
            #pragma unroll
            for (int r = 0; r < 4; ++r) {
                float xa = sp[n0+r] + s*ws[XRAW_OFF + (n0+r)*8 + bcol];
                acc[t][r] = 19.f*xa;
                rr[r] = fmaxf(xa, 0.f);
                ca[t][r] = (5.f + gg[n0+r]) * (1.f/0.6968f);
            }
            if (col < 8)
                store_r4(&rpl[0][col][(TBASE + t)*16 + quad*4], rr[0], rr[1], rr[2], rr[3]);
        }
    }
    __syncthreads();

    // ---- step loop ----
    for (int i = 0; i < T; ++i) {
        const int p = i & 1;
        // wave2: deferred arm ODE for step i-1 (frc[(i-1)&1] written by wave7 last step)
        if (wave == 2 && i > 0) {
            if (lane < 8) {
                float4 o4;
                arm_step_ode(frc[(i-1) & 1], lane, t1, t2, d1, d2, o4);
                obuf[(i-1) & 31][lane] = o4;
            }
            if ((i & 31) == 0) {   // flush steps i-32 .. i-1
                asm volatile("s_waitcnt lgkmcnt(0)" ::: "memory");
                #pragma unroll
                for (int k2 = 0; k2 < 4; ++k2) {
                    int idx = lane + (k2 << 6);
                    int so = idx >> 3, b = idx & 7;
                    *(float4*)(out + ((size_t)(i - 32 + so)*8 + b)*4) = obuf[so][b];
                }
            }
        }
        if (wave == 7) { acc[2][0]=0.f; acc[2][1]=0.f; acc[2][2]=0.f; acc[2][3]=0.f; }

        if (four) {
            #pragma unroll
            for (int kt = 0; kt < 13; ++kt) {
                half8 b = *(const half8*)&rpl[p][bcol][kt*32 + quad*8];
                acc[0] = __builtin_amdgcn_mfma_f32_16x16x32_f16(af[0][kt], b, acc[0], 0, 0, 0);
                acc[1] = __builtin_amdgcn_mfma_f32_16x16x32_f16(af[1][kt], b, acc[1], 0, 0, 0);
                acc[2] = __builtin_amdgcn_mfma_f32_16x16x32_f16(af[2][kt], b, acc[2], 0, 0, 0);
                acc[3] = __builtin_amdgcn_mfma_f32_16x16x32_f16(af[3][kt], b, acc[3], 0, 0, 0);
            }
        } else {
            #pragma unroll
            for (int kt = 0; kt < 13; ++kt) {
                half8 b = *(const half8*)&rpl[p][bcol][kt*32 + quad*8];
                acc[0] = __builtin_amdgcn_mfma_f32_16x16x32_f16(af[0][kt], b, acc[0], 0, 0, 0);
                acc[1] = __builtin_amdgcn_mfma_f32_16x16x32_f16(af[1][kt], b, acc[1], 0, 0, 0);
                acc[2] = __builtin_amdgcn_mfma_f32_16x16x32_f16(af[2][kt], b, acc[2], 0, 0, 0);
            }
        }

        const float tf = (float)(i + 1);
        const float et = __expf(tf * (-1.f/60.f)) - __expf(tf * (-1.f/6.f));
        #pragma unroll
        for (int t = 0; t < 4; ++t) {
            if (t < nW) {
                float rr[4];
                #pragma unroll
                for (int r = 0; r < 4; ++r) {
                    float ya = acc[t][r] + ca[t][r]*et;
                    rr[r] = fmaxf(TAU_X*ya, 0.f);
                    acc[t][r] = 0.95f*ya;
                }
                if (col < 8)
                    store_r4(&rpl[p^1][col][(TBASE + t)*16 + quad*4], rr[0], rr[1], rr[2], rr[3]);
            }
        }
        // wave7: muscle update from Cl-tile accumulator (slot 2)
        if (wave == 7 && col < 8) {
            int sl = i - (i/10)*10;
            #pragma unroll
            for (int r = 0; r < 4; ++r) {
                int m = quad*4 + r;
                if (m < 6) {
                    float mi = acc[2][r] * TAU_M;
                    float mnew = (mi > 0.f ? mi : 0.4f*mi) + 0.8f*msc[r];
                    msc[r] = mnew;
                    float delayed = dbuf[sl][m*8 + col];
                    dbuf[sl][m*8 + col] = mnew;
                    frc[i & 1][m*8 + col] = 40.f * fmaxf(delayed, 0.f);
                }
            }
        }
        __syncthreads();
    }

    // wave2: final deferred ODE for step T-1 + residual flush
    if (wave == 2) {
        if (lane < 8) {
            float4 o4;
            arm_step_ode(frc[(T-1) & 1], lane, t1, t2, d1, d2, o4);
            obuf[(T-1) & 31][lane] = o4;
        }
        asm volatile("s_waitcnt lgkmcnt(0)" ::: "memory");
        const int i0 = (T-1) & ~31;
        const int cnt = T - i0;           // 1..32 steps remaining
        for (int idx = lane; idx < cnt*8; idx += 64) {
            int so = idx >> 3, b = idx & 7;
            *(float4*)(out + ((size_t)(i0 + so)*8 + b)*4) = obuf[so][b];
        }
    }
}

extern "C" void kernel_launch(void* const* d_in, const int* in_sizes, int n_in,
                              void* d_out, int out_size, void* d_ws, size_t ws_size,
                              hipStream_t stream) {
    (void)in_sizes; (void)n_in; (void)out_size; (void)ws_size;
    const int*   Tp   = (const int*)d_in[0];
    const float* des  = (const float*)d_in[1];
    const float* W    = (const float*)d_in[3];
    const float* iw   = (const float*)d_in[4];
    const float* xp   = (const float*)d_in[5];
    const float* cp   = (const float*)d_in[6];
    const float* sp   = (const float*)d_in[7];
    const float* gg   = (const float*)d_in[8];
    const float* topo = (const float*)d_in[9];
    float* ws  = (float*)d_ws;
    float* out = (float*)d_out;

    k_pre1<<<NN, 64, 0, stream>>>(topo, xp, W, sp, iw, des, ws);
    k_pre2<<<1, 64, 0, stream>>>(cp, sp, ws);
    k_run<<<1, TPB, 0, stream>>>(Tp, W, sp, gg, ws, out);
}

// Round 6
// 1699.216 us; speedup vs baseline: 1.9207x; 1.9207x over previous
//
#include <hip/hip_runtime.h>
#include <math.h>

// Problem constants
#define NN 400
#define TPB 512          // 8 waves, 2 waves/SIMD; 3 register A-tiles/wave (fits 256-reg budget),
                         // 2 static tiles (W rows 384-399, muscle-Cl) streamed from LDS
#define KP 424           // padded K stride in fp16 elems

// workspace layout (32-bit indices)
#define XRAW_OFF 1024    // 3200 floats
#define HINP_OFF 4224    // 400 floats
#define CL_OFF   4624    // 2400 floats (projected readout c from k_pre2)

#define TAU_X 0.05f
#define TAU_M 0.2f
#define A1C 0.16f
#define A2C 0.048f
#define A3C 0.045f
#define DHC 0.001f
#define L1C 0.3f
#define L2C 0.33f

typedef unsigned long long ull;
typedef _Float16 f16;
typedef _Float16 __attribute__((ext_vector_type(8))) half8;
typedef float __attribute__((ext_vector_type(4))) f32x4;

// K1: xraw[n][b] = (top_obs @ xstars_prms)[n,b] + xstars_tar[b][n]; hinp[n] = spont[n]-(W@spont)[n]
__global__ __launch_bounds__(64) void k_pre1(const float* __restrict__ topo,
        const float* __restrict__ xp, const float* __restrict__ W,
        const float* __restrict__ sp, const float* __restrict__ iw,
        const float* __restrict__ des, float* __restrict__ ws)
{
    const int n = blockIdx.x, lane = threadIdx.x;
    float a0=0,a1=0,a2=0,a3=0,a4=0,a5=0,a6=0,a7=0, ah=0;
    for (int k = lane; k < NN; k += 64) {
        float to = topo[n*NN + k];
        float wv = W[n*NN + k];
        float s  = sp[k];
        const float* xr = xp + k*8;
        a0 = fmaf(to, xr[0], a0); a1 = fmaf(to, xr[1], a1);
        a2 = fmaf(to, xr[2], a2); a3 = fmaf(to, xr[3], a3);
        a4 = fmaf(to, xr[4], a4); a5 = fmaf(to, xr[5], a5);
        a6 = fmaf(to, xr[6], a6); a7 = fmaf(to, xr[7], a7);
        ah = fmaf(wv, s, ah);
    }
    #pragma unroll
    for (int m = 1; m < 64; m <<= 1) {
        a0 += __shfl_xor(a0, m, 64); a1 += __shfl_xor(a1, m, 64);
        a2 += __shfl_xor(a2, m, 64); a3 += __shfl_xor(a3, m, 64);
        a4 += __shfl_xor(a4, m, 64); a5 += __shfl_xor(a5, m, 64);
        a6 += __shfl_xor(a6, m, 64); a7 += __shfl_xor(a7, m, 64);
        ah += __shfl_xor(ah, m, 64);
    }
    if (lane == 0) {
        float av[8] = {a0,a1,a2,a3,a4,a5,a6,a7};
        float w0 = iw[n*10 + 0], w1 = iw[n*10 + 1];
        #pragma unroll
        for (int b = 0; b < 8; ++b) {
            float j0 = des[2*b]   - 0.25f;
            float j1 = des[2*b+1] - 0.25f;
            ws[XRAW_OFF + n*8 + b] = av[b] + j0*w0 + j1*w1;
        }
        ws[HINP_OFF + n] = sp[n] - ah;
    }
}

// K2: scale s, Gram solve (fp64), Q, Cl precompute
__global__ __launch_bounds__(64) void k_pre2(const float* __restrict__ cp,
        const float* __restrict__ sp, float* __restrict__ ws)
{
    __shared__ float part[99][65];
    __shared__ float red[99];
    const int lane = threadIdx.x;
    float Sxx[36], Sxs[8], Praw[48], Ps[6];
    float Sss = 0.f;
    #pragma unroll
    for (int q = 0; q < 36; ++q) Sxx[q] = 0.f;
    #pragma unroll
    for (int q = 0; q < 8; ++q) Sxs[q] = 0.f;
    #pragma unroll
    for (int q = 0; q < 48; ++q) Praw[q] = 0.f;
    #pragma unroll
    for (int q = 0; q < 6; ++q) Ps[q] = 0.f;

    for (int n = lane; n < NN; n += 64) {
        float xr[8];
        #pragma unroll
        for (int j = 0; j < 8; ++j) xr[j] = ws[XRAW_OFF + n*8 + j];
        float s = sp[n];
        int q = 0;
        #pragma unroll
        for (int i = 0; i < 8; ++i) {
            Sxs[i] = fmaf(xr[i], s, Sxs[i]);
            #pragma unroll
            for (int j = i; j < 8; ++j) { Sxx[q] = fmaf(xr[i], xr[j], Sxx[q]); ++q; }
        }
        Sss = fmaf(s, s, Sss);
        #pragma unroll
        for (int m = 0; m < 6; ++m) {
            float cv = cp[m*NN + n];
            #pragma unroll
            for (int j = 0; j < 8; ++j) Praw[m*8+j] = fmaf(cv, xr[j], Praw[m*8+j]);
            Ps[m] = fmaf(cv, s, Ps[m]);
        }
    }
    #pragma unroll
    for (int q = 0; q < 36; ++q) part[q][lane] = Sxx[q];
    #pragma unroll
    for (int j = 0; j < 8; ++j) part[36+j][lane] = Sxs[j];
    part[44][lane] = Sss;
    #pragma unroll
    for (int q = 0; q < 48; ++q) part[45+q][lane] = Praw[q];
    #pragma unroll
    for (int m = 0; m < 6; ++m) part[93+m][lane] = Ps[m];
    __syncthreads();
    for (int q = lane; q < 99; q += 64) {
        float acc = 0.f;
        for (int l = 0; l < 64; ++l) acc += part[q][l];
        red[q] = acc;
    }
    __syncthreads();
    if (lane == 0) {
        int IDX[8][8];
        { int q = 0; for (int i = 0; i < 8; ++i) for (int j = i; j < 8; ++j) { IDX[i][j]=q; IDX[j][i]=q; ++q; } }
        float sumsq = 0.f;
        for (int i = 0; i < 8; ++i) sumsq += red[IDX[i][i]];
        double s = sqrt(128.0 / (double)sumsq);   // z = N*B*0.2^2
        double Sssd = (double)red[44];
        double G[9][9];
        for (int i = 0; i < 8; ++i)
            for (int j = 0; j < 8; ++j)
                G[i][j] = s*s*(double)red[IDX[i][j]] + s*((double)red[36+i] + (double)red[36+j]) + Sssd;
        for (int i = 0; i < 8; ++i) { G[i][8] = G[8][i] = s*(double)red[36+i] + Sssd; }
        G[8][8] = Sssd;
        double A[9][18];
        for (int i = 0; i < 9; ++i)
            for (int j = 0; j < 9; ++j) { A[i][j] = G[i][j]; A[i][9+j] = (i==j) ? 1.0 : 0.0; }
        for (int col = 0; col < 9; ++col) {
            int piv = col; double mx = fabs(A[col][col]);
            for (int r = col+1; r < 9; ++r) { double v = fabs(A[r][col]); if (v > mx) { mx = v; piv = r; } }
            if (piv != col) for (int j = 0; j < 18; ++j) { double tt = A[col][j]; A[col][j] = A[piv][j]; A[piv][j] = tt; }
            double pv = A[col][col];
            for (int j = 0; j < 18; ++j) A[col][j] /= pv;
            for (int r = 0; r < 9; ++r) if (r != col) {
                double f = A[r][col];
                for (int j = 0; j < 18; ++j) A[r][j] -= f*A[col][j];
            }
        }
        for (int m = 0; m < 6; ++m) {
            double P[9];
            for (int j = 0; j < 8; ++j) P[j] = s*(double)red[45 + m*8 + j] + (double)red[93+m];
            P[8] = (double)red[93+m];
            for (int j = 0; j < 9; ++j) {
                double qv = 0;
                for (int l = 0; l < 9; ++l) qv += P[l]*A[l][9+j];
                ws[2 + m*9 + j] = (float)qv;
            }
        }
        ws[1] = (float)s;
    }
    __syncthreads();
    // Cl[m][n] = cp[m][n] - s*(Q[m,:8].xraw[n,:]) - sp[n]*sum(Q[m,:])
    {
        float s = ws[1];
        for (int idx = lane; idx < 6*NN; idx += 64) {
            int m = idx / NN, n = idx - m*NN;
            float acc = 0.f, sq = 0.f;
            #pragma unroll
            for (int j = 0; j < 8; ++j) {
                float q = ws[2 + m*9 + j];
                acc = fmaf(q, ws[XRAW_OFF + n*8 + j], acc);
                sq += q;
            }
            sq += ws[2 + m*9 + 8];
            ws[CL_OFF + idx] = cp[idx] - s*acc - sp[n]*sq;
        }
    }
}

// A-fragment loader: W[m][k0..k0+7] fp32 -> fp16; k=400 carries h_inp (r row 400 == 1)
__device__ __forceinline__ half8 load_wfrag(const float* __restrict__ Wg,
        const float* __restrict__ ws, int m, int k0)
{
    half8 a;
    if (k0 + 8 <= 400) {
        float4 x0 = *(const float4*)(Wg + m*400 + k0);
        float4 x1 = *(const float4*)(Wg + m*400 + k0 + 4);
        a[0]=(f16)x0.x; a[1]=(f16)x0.y; a[2]=(f16)x0.z; a[3]=(f16)x0.w;
        a[4]=(f16)x1.x; a[5]=(f16)x1.y; a[6]=(f16)x1.z; a[7]=(f16)x1.w;
    } else {
        #pragma unroll
        for (int j = 0; j < 8; ++j) {
            int k = k0 + j;
            float v = 0.f;
            if (k < 400) v = Wg[m*400 + k];
            else if (k == 400) v = ws[HINP_OFF + m];
            a[j] = (f16)v;
        }
    }
    return a;
}

__device__ __forceinline__ void store_r4(f16* dst, float r0, float r1, float r2, float r3) {
    union { f16 h[4]; ull u; } pk;
    pk.h[0] = (f16)r0; pk.h[1] = (f16)r1; pk.h[2] = (f16)r2; pk.h[3] = (f16)r3;
    *(ull*)dst = pk.u;
}

// one Euler step of the 2-link arm + kinematics; lanes 0..7 (one per batch)
__device__ __forceinline__ void arm_step_ode(const float* __restrict__ fr, int lane,
        float& t1, float& t2, float& d1, float& d2, float4& o4)
{
    const float MX[6] = {0.04f,-0.04f,0.f,0.f,0.028f,-0.035f};
    const float MY[6] = {0.f,0.f,0.025f,-0.025f,0.035f,-0.028f};
    float tq0 = 0.f, tq1 = 0.f;
    #pragma unroll
    for (int mm = 0; mm < 6; ++mm) {
        float f = fr[mm*8 + lane];
        tq0 = fmaf(f, MX[mm], tq0);
        tq1 = fmaf(f, MY[mm], tq1);
    }
    float cc2 = cosf(t2), ss2 = sinf(t2);
    float M11 = A1C + 2.f*A2C*cc2;
    float M12 = A3C + A2C*cc2;
    float h = A2C * ss2;
    float C1v = -h * d2 * (2.f*d1 + d2);
    float C2v = h * d1 * d1;
    float rr1 = tq0 - C1v - (0.05f*d1 + 0.025f*d2);
    float rr2 = tq1 - C2v - (0.025f*d1 + 0.05f*d2);
    float det = M11*A3C - M12*M12;
    float dd1 = (A3C*rr1 - M12*rr2) / det;
    float dd2 = (M11*rr2 - M12*rr1) / det;
    t1 += DHC * d1; t2 += DHC * d2;
    d1 += DHC * dd1; d2 += DHC * dd2;
    float t12 = t1 + t2, d12 = d1 + d2;
    float c1v = cosf(t1), s1v = sinf(t1);
    float c12 = cosf(t12), s12 = sinf(t12);
    o4.x = L1C*c1v + L2C*c12;
    o4.y = L1C*s1v + L2C*s12;
    o4.z = -L1C*s1v*d1 - L2C*s12*d12;
    o4.w = L1C*c1v*d1 + L2C*c12*d12;
}

// K3: whole recurrence on ONE CU via MFMA intrinsics; 8 waves (2 per SIMD).
// Register budget per wave at 2 waves/EU is 256 unified regs. Each wave holds
// THREE register A-tiles (af[3][13] = 156 regs) + acc/ca (~32) + temps: fits.
// The two remaining STATIC tiles are staged once into LDS in fragment layout
// and streamed per kt (conflict-free sequential ds_read_b128):
//   wave0 streams W tile 24 (rows 384-399, incl. h_inp bias col)
//   wave7 streams the muscle-Cl tile (muscle preactivation -> acc[3])
// Tile map: wave w owns W tiles 3w, 3w+1, 3w+2 (tiles 0..23).
// wave2: deferred arm ODE + out-ring flush. wave7: muscle state + frc.
__global__ __launch_bounds__(TPB, 2) void k_run(const int* __restrict__ Tp,
        const float* __restrict__ Wg, const float* __restrict__ sp,
        const float* __restrict__ gg, float* __restrict__ ws,
        float* __restrict__ out)
{
    __shared__ __align__(16) f16 rpl[2][8][KP];       // r planes [batch(8)][neuron k(424)]
    __shared__ __align__(16) f16 at2[2][13][64][8];   // streamed tiles in fragment layout
    __shared__ float dbuf[10][48];                    // muscle delay ring (wave7)
    __shared__ float frc[2][48];                      // double-buffered: w7 writes, w2 reads
    __shared__ float4 obuf[32][8];                    // 32-step cart out-ring (wave2)

    const int tid = threadIdx.x;
    const int T = *Tp;
    const int wave = tid >> 6, lane = tid & 63;
    const int quad = lane >> 4, col = lane & 15;
    const int bcol = col & 7;
    const float s = ws[1];

    // ---- LDS init ----
    for (int idx = tid; idx < 2*8*KP; idx += TPB) ((f16*)rpl)[idx] = (f16)0.f;
    // streamed-tile staging: fragment layout [s][kt][lane][j]
    for (int idx = tid; idx < 2*13*512; idx += TPB) {
        int ss   = idx / (13*512);
        int rem  = idx - ss*(13*512);
        int kt   = rem >> 9;
        int rem2 = rem & 511;
        int ln   = rem2 >> 3, j = rem2 & 7;
        int c_   = ln & 15, q_ = ln >> 4;
        int k    = kt*32 + q_*8 + j;
        float v = 0.f;
        if (ss == 0) {
            if (k < 400) v = Wg[(384 + c_)*400 + k];
            else if (k == 400) v = ws[HINP_OFF + 384 + c_];
        } else {
            if (c_ < 6 && k < 400) v = ws[CL_OFF + c_*400 + k];
        }
        ((f16*)at2)[idx] = (f16)v;
    }
    for (int idx = tid; idx < 480; idx += TPB) ((float*)dbuf)[idx] = 0.f;
    for (int idx = tid; idx < 96; idx += TPB) ((float*)frc)[idx] = 0.f;
    __syncthreads();
    if (tid < 8) { rpl[0][tid][400] = (f16)1.f; rpl[1][tid][400] = (f16)1.f; }

    // ---- register A-tiles: af[t][kt], tiles 3w..3w+2 ----
    half8 af[3][13];
    #pragma unroll
    for (int t = 0; t < 3; ++t) {
        #pragma unroll
        for (int kt = 0; kt < 13; ++kt)
            af[t][kt] = load_wfrag(Wg, ws, (3*wave + t)*16 + col, kt*32 + quad*8);
    }

    // ---- state init: acc = 19*x0 (x lives in accumulator scaled by (1-tau)/tau) ----
    const int nT = (wave == 0) ? 4 : 3;    // epilogue tiles (wave0's t=3 = rows 384-399)
    f32x4 acc[4];
    float ca[4][4];
    float msc[4] = {0.f, 0.f, 0.f, 0.f};
    float t1 = 1.f, t2 = 1.f, d1 = 0.f, d2 = 0.f;   // wave2 lanes 0..7
    #pragma unroll
    for (int t = 0; t < 4; ++t)
        #pragma unroll
        for (int r = 0; r < 4; ++r) { acc[t][r] = 0.f; ca[t][r] = 0.f; }
    #pragma unroll
    for (int t = 0; t < 4; ++t) {
        if (t < nT) {
            int n0 = (t < 3) ? (3*wave + t)*16 + quad*4 : 384 + quad*4;
            float rr[4];
            #pragma unroll
            for (int r = 0; r < 4; ++r) {
                float xa = sp[n0+r] + s*ws[XRAW_OFF + (n0+r)*8 + bcol];
                acc[t][r] = 19.f*xa;
                rr[r] = fmaxf(xa, 0.f);
                ca[t][r] = (5.f + gg[n0+r]) * (1.f/0.6968f);
            }
            if (col < 8)
                store_r4(&rpl[0][col][n0], rr[0], rr[1], rr[2], rr[3]);
        }
    }
    __syncthreads();

    // ---- step loop ----
    for (int i = 0; i < T; ++i) {
        const int p = i & 1;
        // wave2: deferred arm ODE for step i-1 (frc[(i-1)&1] written by wave7 last step)
        if (wave == 2 && i > 0) {
            if (lane < 8) {
                float4 o4;
                arm_step_ode(frc[(i-1) & 1], lane, t1, t2, d1, d2, o4);
                obuf[(i-1) & 31][lane] = o4;
            }
            if ((i & 31) == 0) {   // flush steps i-32 .. i-1
                asm volatile("s_waitcnt lgkmcnt(0)" ::: "memory");
                #pragma unroll
                for (int k2 = 0; k2 < 4; ++k2) {
                    int idx = lane + (k2 << 6);
                    int so = idx >> 3, b = idx & 7;
                    *(float4*)(out + ((size_t)(i - 32 + so)*8 + b)*4) = obuf[so][b];
                }
            }
        }
        if (wave == 7) { acc[3][0]=0.f; acc[3][1]=0.f; acc[3][2]=0.f; acc[3][3]=0.f; }

        if (wave == 0 || wave == 7) {
            const int sidx = (wave == 7) ? 1 : 0;
            #pragma unroll
            for (int kt = 0; kt < 13; ++kt) {
                half8 b  = *(const half8*)&rpl[p][bcol][kt*32 + quad*8];
                half8 a3 = *(const half8*)&at2[sidx][kt][lane][0];
                acc[0] = __builtin_amdgcn_mfma_f32_16x16x32_f16(af[0][kt], b, acc[0], 0, 0, 0);
                acc[1] = __builtin_amdgcn_mfma_f32_16x16x32_f16(af[1][kt], b, acc[1], 0, 0, 0);
                acc[2] = __builtin_amdgcn_mfma_f32_16x16x32_f16(af[2][kt], b, acc[2], 0, 0, 0);
                acc[3] = __builtin_amdgcn_mfma_f32_16x16x32_f16(a3,       b, acc[3], 0, 0, 0);
            }
        } else {
            #pragma unroll
            for (int kt = 0; kt < 13; ++kt) {
                half8 b = *(const half8*)&rpl[p][bcol][kt*32 + quad*8];
                acc[0] = __builtin_amdgcn_mfma_f32_16x16x32_f16(af[0][kt], b, acc[0], 0, 0, 0);
                acc[1] = __builtin_amdgcn_mfma_f32_16x16x32_f16(af[1][kt], b, acc[1], 0, 0, 0);
                acc[2] = __builtin_amdgcn_mfma_f32_16x16x32_f16(af[2][kt], b, acc[2], 0, 0, 0);
            }
        }

        const float tf = (float)(i + 1);
        const float et = __expf(tf * (-1.f/60.f)) - __expf(tf * (-1.f/6.f));
        #pragma unroll
        for (int t = 0; t < 4; ++t) {
            if (t < nT) {
                int n0 = (t < 3) ? (3*wave + t)*16 + quad*4 : 384 + quad*4;
                float rr[4];
                #pragma unroll
                for (int r = 0; r < 4; ++r) {
                    float ya = acc[t][r] + ca[t][r]*et;
                    rr[r] = fmaxf(TAU_X*ya, 0.f);
                    acc[t][r] = 0.95f*ya;
                }
                if (col < 8)
                    store_r4(&rpl[p^1][col][n0], rr[0], rr[1], rr[2], rr[3]);
            }
        }
        // wave7: muscle update from streamed Cl accumulator (slot 3)
        if (wave == 7 && col < 8) {
            int sl = i - (i/10)*10;
            #pragma unroll
            for (int r = 0; r < 4; ++r) {
                int m = quad*4 + r;
                if (m < 6) {
                    float mi = acc[3][r] * TAU_M;
                    float mnew = (mi > 0.f ? mi : 0.4f*mi) + 0.8f*msc[r];
                    msc[r] = mnew;
                    float delayed = dbuf[sl][m*8 + col];
                    dbuf[sl][m*8 + col] = mnew;
                    frc[i & 1][m*8 + col] = 40.f * fmaxf(delayed, 0.f);
                }
            }
        }
        __syncthreads();
    }

    // wave2: final deferred ODE for step T-1 + residual flush
    if (wave == 2) {
        if (lane < 8) {
            float4 o4;
            arm_step_ode(frc[(T-1) & 1], lane, t1, t2, d1, d2, o4);
            obuf[(T-1) & 31][lane] = o4;
        }
        asm volatile("s_waitcnt lgkmcnt(0)" ::: "memory");
        const int i0 = (T-1) & ~31;
        const int cnt = T - i0;           // 1..32 steps remaining
        for (int idx = lane; idx < cnt*8; idx += 64) {
            int so = idx >> 3, b = idx & 7;
            *(float4*)(out + ((size_t)(i0 + so)*8 + b)*4) = obuf[so][b];
        }
    }
}

extern "C" void kernel_launch(void* const* d_in, const int* in_sizes, int n_in,
                              void* d_out, int out_size, void* d_ws, size_t ws_size,
                              hipStream_t stream) {
    (void)in_sizes; (void)n_in; (void)out_size; (void)ws_size;
    const int*   Tp   = (const int*)d_in[0];
    const float* des  = (const float*)d_in[1];
    const float* W    = (const float*)d_in[3];
    const float* iw   = (const float*)d_in[4];
    const float* xp   = (const float*)d_in[5];
    const float* cp   = (const float*)d_in[6];
    const float* sp   = (const float*)d_in[7];
    const float* gg   = (const float*)d_in[8];
    const float* topo = (const float*)d_in[9];
    float* ws  = (float*)d_ws;
    float* out = (float*)d_out;

    k_pre1<<<NN, 64, 0, stream>>>(topo, xp, W, sp, iw, des, ws);
    k_pre2<<<1, 64, 0, stream>>>(cp, sp, ws);
    k_run<<<1, TPB, 0, stream>>>(Tp, W, sp, gg, ws, out);
}